// Round 6
// baseline (1040.713 us; speedup 1.0000x reference)
//
#include <hip/hip_runtime.h>
#include <hip/hip_fp16.h>

// ============================================================================
// ABSA LSTM on MI355X — Round 6: reg-resident Wx+Wh, batched issue-ahead poll
//
//  B=1024, T=80, V=50000, D=H=300, 4H=1200, C=3.
//  256 persistent blocks = 64 groups (16 batch rows) x 4 hidden-slices (75).
//  Per block: 4 waves, wave w = gate w, 5 N-tiles of 16 (80 cols >= 75).
//
//  ERRATA r4: FETCH/WRITE are KB -> round 3 moved 53+99 MB, NOT GB. No spill
//  ever happened (weights live in the unified AGPR half). Streaming Wx from
//  L2 (r4/r5) added ~1.3us/step of per-CU L2 port time on the critical path;
//  the per-chunk serial retry added up to 20 L3 RTTs/step. Both reverted:
//   - Wx AND Wh register-resident (400 regs, r3-proven); xpart is kt-outer
//     (one live xa frag) and costs ~0.3us.
//   - Poll loads for h(t) ISSUE right after the h(t) stores, pinned by
//     sched_barrier(0); RTT hides under xpart(t+1). Retry loop rechecks all
//     20 chunks per pass, reloads only stale ones in parallel (1 RTT/retry).
//  Tag sync unchanged: tag=(t mod 15) in bit0 of each fp16 (<=1 ulp), ring
//  of 8 slabs, virgin=0xFF (tag 15 invalid). One __syncthreads per step.
// ============================================================================

typedef float    f32x4 __attribute__((ext_vector_type(4)));
typedef _Float16 f16;
typedef _Float16 f16x8 __attribute__((ext_vector_type(8)));
typedef unsigned long long u64;

#define NB    1024
#define TT    80
#define NV    50000
#define ND    300
#define KP    320      // padded K: 10 tiles of 32 (300 real + bias row 300)
#define NKT   10
#define SL    75       // hidden cols per slice
#define SLP   80       // physical slice stride in hbuf row (4*80 = 320 = KP)
#define NTPG  5        // 16-col N-tiles per gate per block
#define NTIL  20       // 4 gates * 5
#define TPB   256      // 4 waves
#define GRID  256
#define NSLAB 8

#define TAGMASK 0x0001000100010001ULL

// ---- ws layout (bytes) ----
#define OFF_EMB   0                        // 50000*320*2 = 32,000,000
#define OFF_WHP   32000000                 // 4*20*10*512*2 = 819,200
#define OFF_WXP   32819200
#define OFF_HBUF  33638400                 // 8 slabs * 1024*320*2 = 5,242,880
#define HBUF_SZ   (NB * KP)                // elements per slab
#define OFF_HF32  38881280                 // 1024*300*4 = 1,228,800
#define WS_NEED   40110080

// emb f32[50000][300] -> fp16 [50000][320]; col 300 = 1.0 (bias row), >300 = 0
__global__ __launch_bounds__(256) void absa_prep_emb(
    const float* __restrict__ emb, f16* __restrict__ embb) {
  int i = blockIdx.x * 256 + threadIdx.x;
  if (i >= NV * KP / 8) return;
  int flat = i * 8;
  int row  = flat / KP;
  int k    = flat - row * KP;
  f16x8 o;
  if (k + 7 < ND) {
    float4 a = *reinterpret_cast<const float4*>(emb + row * ND + k);
    float4 b = *reinterpret_cast<const float4*>(emb + row * ND + k + 4);
    o[0] = (f16)a.x; o[1] = (f16)a.y; o[2] = (f16)a.z; o[3] = (f16)a.w;
    o[4] = (f16)b.x; o[5] = (f16)b.y; o[6] = (f16)b.z; o[7] = (f16)b.w;
  } else {
#pragma unroll
    for (int e = 0; e < 8; ++e) {
      int kk = k + e;
      float v = (kk < ND) ? emb[row * ND + kk] : (kk == ND ? 1.0f : 0.0f);
      o[e] = (f16)v;
    }
  }
  *reinterpret_cast<f16x8*>(embb + flat) = o;
}

// Pack Wx (mode 0, with bias at k==300) and Wh (mode 1, 4x80-phys k blocks)
// into [n<4][nt<20][kt<10][lane<64][e<8] fp16 frags.
__global__ __launch_bounds__(256) void absa_prep_pack2(
    const float* __restrict__ Wx, const float* __restrict__ Wh,
    const float* __restrict__ bias,
    f16* __restrict__ wxp, f16* __restrict__ whp) {
  const int half = 4 * NTIL * NKT * 512;    // 409,600
  int idx0 = blockIdx.x * 256 + threadIdx.x;
  if (idx0 >= 2 * half) return;
  int mode = idx0 >= half;
  int idx  = idx0 - mode * half;
  int e    = idx & 7;
  int lane = (idx >> 3) & 63;
  int fid  = idx >> 9;
  int kt   = fid % NKT;
  int rem  = fid / NKT;
  int nt   = rem % NTIL;
  int n    = rem / NTIL;
  int gi   = nt / NTPG, ti = nt - gi * NTPG;
  int k    = kt * 32 + (lane >> 4) * 8 + e;
  int cc   = ti * 16 + (lane & 15);
  float v = 0.f;
  if (cc < SL) {
    int col = gi * 300 + n * SL + cc;
    if (mode == 0) {
      if (k < ND)       v = Wx[k * 1200 + col];
      else if (k == ND) v = bias[col];
    } else {
      int kl = k % SLP, n2 = k / SLP;
      if (kl < SL)      v = Wh[(n2 * SL + kl) * 1200 + col];
    }
  }
  (mode ? whp : wxp)[idx] = (f16)v;
}

__device__ __forceinline__ float sigf(float x) {
  return __builtin_amdgcn_rcpf(1.f + __builtin_amdgcn_exp2f(-1.44269504f * x));
}
__device__ __forceinline__ float tanhf_(float x) {
  float xx = fminf(15.f, fmaxf(-15.f, x));
  return 1.f - 2.f * __builtin_amdgcn_rcpf(1.f + __builtin_amdgcn_exp2f(2.88539008f * xx));
}

__device__ __forceinline__ u64 tag_pat(int tg) {
  return ((u64)(tg & 1)) | ((u64)((tg >> 1) & 1) << 16) |
         ((u64)((tg >> 2) & 1) << 32) | ((u64)((tg >> 3) & 1) << 48);
}

__global__ __launch_bounds__(TPB, 1) void absa_lstm(
    const int* __restrict__ sent, const int* __restrict__ lens,
    const f16* __restrict__ embb,
    const f16* __restrict__ whp, const f16* __restrict__ wxp,
    f16* __restrict__ hbuf, float* __restrict__ hf32) {
  const int bid = blockIdx.x;
  const int s   = bid & 7;           // partners share s => same-XCD heuristic
  const int q   = bid >> 3;
  const int n   = q & 3;             // hidden slice
  const int g   = s * 8 + (q >> 2);  // batch group (16 rows)

  const int tid = threadIdx.x;
  const int w   = tid >> 6;          // wave = gate
  const int l   = tid & 63;
  const int l15 = l & 15, lk = l >> 4;
  const int grow0 = g * 16;

  __shared__ float gates[2 * 4 * 80 * 20];   // dbuf [parity][gate][col][row20]
  __shared__ float c_lds[80 * 20];
  __shared__ float hf_lds[80 * 20];
  __shared__ int   sent_lds[16 * TT];
  __shared__ int   len_lds[16];

  for (int i = tid; i < 16 * TT; i += TPB) sent_lds[i] = sent[g * 16 * TT + i];
  if (tid < 16) len_lds[tid] = lens[grow0 + tid];
  for (int i = tid; i < 80 * 20; i += TPB) { c_lds[i] = 0.f; hf_lds[i] = 0.f; }
  __syncthreads();

  int maxlen = 0;
#pragma unroll
  for (int r = 0; r < 16; ++r) maxlen = max(maxlen, len_lds[r]);

  // ---- Wx AND Wh register-resident (r3-proven: no spill, AGPR half used) --
  f16x8 wh[NTPG][NKT], wx[NTPG][NKT];
#pragma unroll
  for (int j = 0; j < NTPG; ++j)
#pragma unroll
    for (int kt = 0; kt < NKT; ++kt) {
      size_t off = ((size_t)(n * NTIL + (w * NTPG + j)) * NKT + kt) * 512 + l * 8;
      wh[j][kt] = *reinterpret_cast<const f16x8*>(whp + off);
      wx[j][kt] = *reinterpret_cast<const f16x8*>(wxp + off);
    }

  int gaddr[NTPG];
#pragma unroll
  for (int j = 0; j < NTPG; ++j)
    gaddr[j] = ((w * 80) + j * 16 + l15) * 20 + lk * 4;

  f32x4 acc[NTPG];
  u64 q0[NKT], q1[NKT];

  // x-part: kt-outer so only ONE xa frag is live (reg pressure)
  auto xpart = [&](int t) {
#pragma unroll
    for (int j = 0; j < NTPG; ++j) acc[j] = (f32x4){0.f, 0.f, 0.f, 0.f};
    const int srow = sent_lds[l15 * TT + t];
    const f16* xb = embb + (size_t)srow * KP + lk * 8;
#pragma unroll
    for (int kt = 0; kt < NKT; ++kt) {
      f16x8 xa = *reinterpret_cast<const f16x8*>(xb + kt * 32);
#pragma unroll
      for (int j = 0; j < NTPG; ++j)
        acc[j] = __builtin_amdgcn_mfma_f32_16x16x32_f16(xa, wx[j][kt], acc[j], 0, 0, 0);
    }
  };

  xpart(0);

  for (int t = 0; t < maxlen; ++t) {
    const int par = (t & 1) * (4 * 80 * 20);

    // ---- h(t-1): batched check/retry on loads issued at end of step t-1 ----
    if (t > 0) {
      const u64 expv = tag_pat((t - 1) % 15);
      const f16* hp = hbuf + (size_t)((t - 1) & 7) * HBUF_SZ + (grow0 + l15) * KP + lk * 8;
      bool any = true;
      int guard = 0;
      while (any && guard++ < (1 << 14)) {   // each pass = 1 L3 RTT for all stale
        any = false;
#pragma unroll
        for (int kt = 0; kt < NKT; ++kt) {
          const u64* p = reinterpret_cast<const u64*>(hp + kt * 32);
          if ((q0[kt] & TAGMASK) != expv) {
            q0[kt] = __hip_atomic_load(p,     __ATOMIC_RELAXED, __HIP_MEMORY_SCOPE_AGENT);
            any = true;
          }
          if ((q1[kt] & TAGMASK) != expv) {
            q1[kt] = __hip_atomic_load(p + 1, __ATOMIC_RELAXED, __HIP_MEMORY_SCOPE_AGENT);
            any = true;
          }
        }
      }
#pragma unroll
      for (int kt = 0; kt < NKT; ++kt) {
        union { u64 qq[2]; f16x8 v; } u;
        u.qq[0] = q0[kt]; u.qq[1] = q1[kt];
#pragma unroll
        for (int j = 0; j < NTPG; ++j)
          acc[j] = __builtin_amdgcn_mfma_f32_16x16x32_f16(u.v, wh[j][kt], acc[j], 0, 0, 0);
      }
    }

    // ---- C-tiles -> LDS (parity buffer), one barrier per step ----
#pragma unroll
    for (int j = 0; j < NTPG; ++j)
      *reinterpret_cast<f32x4*>(&gates[par + gaddr[j]]) = acc[j];
    __syncthreads();

    // ---- elementwise + tagged u64 h stores into slab t&7 ----
    {
      const u64 pat = tag_pat(t % 15);
      f16* hc = hbuf + (size_t)(t & 7) * HBUF_SZ;
      for (int i = tid; i < 320; i += TPB) {   // (row, col-quad)
        int row = i & 15, qd = i >> 4;
        union { unsigned short us[4]; u64 uu; } pu;
#pragma unroll
        for (int e = 0; e < 4; ++e) {
          int cc = qd * 4 + e;
          float h = 0.f;
          if (cc < SL) {
            int base = cc * 20 + row;
            if (t < len_lds[row]) {
              float vi = gates[par + (0 * 80 + cc) * 20 + row];
              float vf = gates[par + (1 * 80 + cc) * 20 + row];
              float vg = gates[par + (2 * 80 + cc) * 20 + row];
              float vo = gates[par + (3 * 80 + cc) * 20 + row];
              float iv = sigf(vi), fv = sigf(vf), ov = sigf(vo);
              float gv = tanhf_(vg);
              float cn = fv * c_lds[base] + iv * gv;
              h = ov * tanhf_(cn);
              c_lds[base] = cn;
              hf_lds[base] = h;
            } else {
              h = hf_lds[base];
            }
          }
          union { f16 f; unsigned short u; } cv;
          cv.f = (f16)h;
          pu.us[e] = cv.u;
        }
        pu.uu = (pu.uu & ~TAGMASK) | pat;      // tag in bit0 of each fp16
        u64* dst = reinterpret_cast<u64*>(hc + (size_t)(grow0 + row) * KP + n * SLP + qd * 4);
        __hip_atomic_store(dst, pu.uu, __ATOMIC_RELAXED, __HIP_MEMORY_SCOPE_AGENT);
      }
    }

    // ---- issue-ahead: first poll attempt for h(t) flies under xpart(t+1) ----
    if (t + 1 < maxlen) {
      const f16* hpn = hbuf + (size_t)(t & 7) * HBUF_SZ + (grow0 + l15) * KP + lk * 8;
#pragma unroll
      for (int kt = 0; kt < NKT; ++kt) {
        const u64* p = reinterpret_cast<const u64*>(hpn + kt * 32);
        q0[kt] = __hip_atomic_load(p,     __ATOMIC_RELAXED, __HIP_MEMORY_SCOPE_AGENT);
        q1[kt] = __hip_atomic_load(p + 1, __ATOMIC_RELAXED, __HIP_MEMORY_SCOPE_AGENT);
      }
      __builtin_amdgcn_sched_barrier(0);       // pin issue before xpart
      xpart(t + 1);
    }
  }

  __syncthreads();
  for (int i = tid; i < 16 * SL; i += TPB) {
    int row = i & 15, cc = i >> 4;
    hf32[(grow0 + row) * ND + n * SL + cc] = hf_lds[cc * 20 + row];
  }
}

__global__ __launch_bounds__(256) void absa_logits(
    const float* __restrict__ hf32, const float* __restrict__ Wout,
    const float* __restrict__ bout, float* __restrict__ out) {
  int row = blockIdx.x * 4 + (threadIdx.x >> 6);   // 1 wave per batch row
  int l   = threadIdx.x & 63;
  float s0 = 0.f, s1 = 0.f, s2 = 0.f;
  for (int k = l; k < ND; k += 64) {
    float h  = hf32[row * ND + k];
    s0 += h * Wout[k * 3 + 0];
    s1 += h * Wout[k * 3 + 1];
    s2 += h * Wout[k * 3 + 2];
  }
#pragma unroll
  for (int o = 32; o; o >>= 1) {
    s0 += __shfl_down(s0, o);
    s1 += __shfl_down(s1, o);
    s2 += __shfl_down(s2, o);
  }
  if (l == 0) {
    out[row * 3 + 0] = s0 + bout[0];
    out[row * 3 + 1] = s1 + bout[1];
    out[row * 3 + 2] = s2 + bout[2];
  }
}

extern "C" void kernel_launch(void* const* d_in, const int* in_sizes, int n_in,
                              void* d_out, int out_size, void* d_ws, size_t ws_size,
                              hipStream_t stream) {
  const int*   sent = (const int*)d_in[0];
  const int*   lens = (const int*)d_in[1];
  const float* emb  = (const float*)d_in[2];
  const float* Wx   = (const float*)d_in[3];
  const float* Wh   = (const float*)d_in[4];
  const float* bv   = (const float*)d_in[5];
  const float* Wout = (const float*)d_in[6];
  const float* bout = (const float*)d_in[7];
  float* out = (float*)d_out;

  char* wsb = (char*)d_ws;
  f16*   embb = (f16*)(wsb + OFF_EMB);
  f16*   whp  = (f16*)(wsb + OFF_WHP);
  f16*   wxp  = (f16*)(wsb + OFF_WXP);
  f16*   hbuf = (f16*)(wsb + OFF_HBUF);
  float* hf32 = (float*)(wsb + OFF_HF32);

  // virgin slabs = 0xFF: tag bits 1111 (=15, outside 0..14) + NaN fp16 data
  (void)hipMemsetAsync(hbuf, 0xFF, NSLAB * NB * KP * 2, stream);

  absa_prep_emb  <<<(NV * KP / 8 + 255) / 256, 256, 0, stream>>>(emb, embb);
  absa_prep_pack2<<<2 * 4 * NTIL * NKT * 512 / 256, 256, 0, stream>>>(Wx, Wh, bv, wxp, whp);
  absa_lstm      <<<GRID, TPB, 0, stream>>>(sent, lens, embb, whp, wxp, hbuf, hf32);
  absa_logits    <<<NB / 4, 256, 0, stream>>>(hf32, Wout, bout, out);
}

// Round 8
// 685.497 us; speedup vs baseline: 1.5182x; 1.5182x over previous
//
#include <hip/hip_runtime.h>
#include <hip/hip_fp16.h>

// ============================================================================
// ABSA LSTM on MI355X — Round 7 resubmit (round 7 hit GPU-acquisition timeout)
// RMW h-stores (visibility fix) + r3 reg layout.
//
//  B=1024, T=80, V=50000, D=H=300, 4H=1200, C=3.
//  256 persistent blocks = 64 groups (16 batch rows) x 4 hidden-slices (75).
//  Per block: 4 waves, wave w = gate w, 5 N-tiles of 16 (80 cols >= 75).
//
//  Round-6 lessons:
//   - Issue-ahead poll held 40 extra VGPRs live across xpart -> allocator hit
//     the 256 cap and rematerialized weight frags from global every step
//     (FETCH +48 MB, reads-no-writes signature). Reverted; poll state is
//     loop-local again, both Wx+Wh register-resident (r3-proven, VGPR 248).
//   - CORE FIX: relaxed agent atomic STORES are write-back into the
//     producer's XCD-L2; remote readers hit L3 which does NOT back-probe
//     dirty remote L2 lines -> tag visibility was EVICTION-DRIVEN (~5us,
//     random; explains r3/r5/r6 all ~6.7-12us/step and the 41ms outlier).
//     h-stores are now __hip_atomic_exchange (RMW executes at the L3
//     coherence point -> immediate visibility, ~1.25 RMW/thread/step).
//  Tag sync unchanged: tag=(t mod 15) in bit0 of each fp16 (<=1 ulp), ring
//  of 8 slabs, virgin=0xFF (tag 15 invalid). One __syncthreads per step.
// ============================================================================

typedef float    f32x4 __attribute__((ext_vector_type(4)));
typedef _Float16 f16;
typedef _Float16 f16x8 __attribute__((ext_vector_type(8)));
typedef unsigned long long u64;

#define NB    1024
#define TT    80
#define NV    50000
#define ND    300
#define KP    320      // padded K: 10 tiles of 32 (300 real + bias row 300)
#define NKT   10
#define SL    75       // hidden cols per slice
#define SLP   80       // physical slice stride in hbuf row (4*80 = 320 = KP)
#define NTPG  5        // 16-col N-tiles per gate per block
#define NTIL  20       // 4 gates * 5
#define TPB   256      // 4 waves
#define GRID  256
#define NSLAB 8

#define TAGMASK 0x0001000100010001ULL

// ---- ws layout (bytes) ----
#define OFF_EMB   0                        // 50000*320*2 = 32,000,000
#define OFF_WHP   32000000                 // 4*20*10*512*2 = 819,200
#define OFF_WXP   32819200
#define OFF_HBUF  33638400                 // 8 slabs * 1024*320*2 = 5,242,880
#define HBUF_SZ   (NB * KP)                // elements per slab
#define OFF_HF32  38881280                 // 1024*300*4 = 1,228,800
#define WS_NEED   40110080

// emb f32[50000][300] -> fp16 [50000][320]; col 300 = 1.0 (bias row), >300 = 0
__global__ __launch_bounds__(256) void absa_prep_emb(
    const float* __restrict__ emb, f16* __restrict__ embb) {
  int i = blockIdx.x * 256 + threadIdx.x;
  if (i >= NV * KP / 8) return;
  int flat = i * 8;
  int row  = flat / KP;
  int k    = flat - row * KP;
  f16x8 o;
  if (k + 7 < ND) {
    float4 a = *reinterpret_cast<const float4*>(emb + row * ND + k);
    float4 b = *reinterpret_cast<const float4*>(emb + row * ND + k + 4);
    o[0] = (f16)a.x; o[1] = (f16)a.y; o[2] = (f16)a.z; o[3] = (f16)a.w;
    o[4] = (f16)b.x; o[5] = (f16)b.y; o[6] = (f16)b.z; o[7] = (f16)b.w;
  } else {
#pragma unroll
    for (int e = 0; e < 8; ++e) {
      int kk = k + e;
      float v = (kk < ND) ? emb[row * ND + kk] : (kk == ND ? 1.0f : 0.0f);
      o[e] = (f16)v;
    }
  }
  *reinterpret_cast<f16x8*>(embb + flat) = o;
}

// Pack Wx (mode 0, with bias at k==300) and Wh (mode 1, 4x80-phys k blocks)
// into [n<4][nt<20][kt<10][lane<64][e<8] fp16 frags.
__global__ __launch_bounds__(256) void absa_prep_pack2(
    const float* __restrict__ Wx, const float* __restrict__ Wh,
    const float* __restrict__ bias,
    f16* __restrict__ wxp, f16* __restrict__ whp) {
  const int half = 4 * NTIL * NKT * 512;    // 409,600
  int idx0 = blockIdx.x * 256 + threadIdx.x;
  if (idx0 >= 2 * half) return;
  int mode = idx0 >= half;
  int idx  = idx0 - mode * half;
  int e    = idx & 7;
  int lane = (idx >> 3) & 63;
  int fid  = idx >> 9;
  int kt   = fid % NKT;
  int rem  = fid / NKT;
  int nt   = rem % NTIL;
  int n    = rem / NTIL;
  int gi   = nt / NTPG, ti = nt - gi * NTPG;
  int k    = kt * 32 + (lane >> 4) * 8 + e;
  int cc   = ti * 16 + (lane & 15);
  float v = 0.f;
  if (cc < SL) {
    int col = gi * 300 + n * SL + cc;
    if (mode == 0) {
      if (k < ND)       v = Wx[k * 1200 + col];
      else if (k == ND) v = bias[col];
    } else {
      int kl = k % SLP, n2 = k / SLP;
      if (kl < SL)      v = Wh[(n2 * SL + kl) * 1200 + col];
    }
  }
  (mode ? whp : wxp)[idx] = (f16)v;
}

__device__ __forceinline__ float sigf(float x) {
  return __builtin_amdgcn_rcpf(1.f + __builtin_amdgcn_exp2f(-1.44269504f * x));
}
__device__ __forceinline__ float tanhf_(float x) {
  float xx = fminf(15.f, fmaxf(-15.f, x));
  return 1.f - 2.f * __builtin_amdgcn_rcpf(1.f + __builtin_amdgcn_exp2f(2.88539008f * xx));
}

__device__ __forceinline__ u64 tag_pat(int tg) {
  return ((u64)(tg & 1)) | ((u64)((tg >> 1) & 1) << 16) |
         ((u64)((tg >> 2) & 1) << 32) | ((u64)((tg >> 3) & 1) << 48);
}

__global__ __launch_bounds__(TPB, 1) void absa_lstm(
    const int* __restrict__ sent, const int* __restrict__ lens,
    const f16* __restrict__ embb,
    const f16* __restrict__ whp, const f16* __restrict__ wxp,
    f16* __restrict__ hbuf, float* __restrict__ hf32) {
  const int bid = blockIdx.x;
  const int s   = bid & 7;           // partners share s => same-XCD heuristic
  const int q   = bid >> 3;
  const int n   = q & 3;             // hidden slice
  const int g   = s * 8 + (q >> 2);  // batch group (16 rows)

  const int tid = threadIdx.x;
  const int w   = tid >> 6;          // wave = gate
  const int l   = tid & 63;
  const int l15 = l & 15, lk = l >> 4;
  const int grow0 = g * 16;

  __shared__ float gates[2 * 4 * 80 * 20];   // dbuf [parity][gate][col][row20]
  __shared__ float c_lds[80 * 20];
  __shared__ float hf_lds[80 * 20];
  __shared__ int   sent_lds[16 * TT];
  __shared__ int   len_lds[16];

  for (int i = tid; i < 16 * TT; i += TPB) sent_lds[i] = sent[g * 16 * TT + i];
  if (tid < 16) len_lds[tid] = lens[grow0 + tid];
  for (int i = tid; i < 80 * 20; i += TPB) { c_lds[i] = 0.f; hf_lds[i] = 0.f; }
  __syncthreads();

  int maxlen = 0;
#pragma unroll
  for (int r = 0; r < 16; ++r) maxlen = max(maxlen, len_lds[r]);

  // ---- Wx AND Wh register-resident (r3 layout: VGPR+AGPR split, no remat) --
  f16x8 wh[NTPG][NKT], wx[NTPG][NKT];
#pragma unroll
  for (int j = 0; j < NTPG; ++j)
#pragma unroll
    for (int kt = 0; kt < NKT; ++kt) {
      size_t off = ((size_t)(n * NTIL + (w * NTPG + j)) * NKT + kt) * 512 + l * 8;
      wh[j][kt] = *reinterpret_cast<const f16x8*>(whp + off);
      wx[j][kt] = *reinterpret_cast<const f16x8*>(wxp + off);
    }

  int gaddr[NTPG];
#pragma unroll
  for (int j = 0; j < NTPG; ++j)
    gaddr[j] = ((w * 80) + j * 16 + l15) * 20 + lk * 4;

  f32x4 acc[NTPG];

  // x-part: kt-outer so only ONE xa frag is live
  auto xpart = [&](int t) {
#pragma unroll
    for (int j = 0; j < NTPG; ++j) acc[j] = (f32x4){0.f, 0.f, 0.f, 0.f};
    const int srow = sent_lds[l15 * TT + t];
    const f16* xb = embb + (size_t)srow * KP + lk * 8;
#pragma unroll
    for (int kt = 0; kt < NKT; ++kt) {
      f16x8 xa = *reinterpret_cast<const f16x8*>(xb + kt * 32);
#pragma unroll
      for (int j = 0; j < NTPG; ++j)
        acc[j] = __builtin_amdgcn_mfma_f32_16x16x32_f16(xa, wx[j][kt], acc[j], 0, 0, 0);
    }
  };

  xpart(0);

  for (int t = 0; t < maxlen; ++t) {
    const int par = (t & 1) * (4 * 80 * 20);

    // ---- acquire h(t-1): parallel-issue poll, batched stale-only retry ----
    if (t > 0) {
      const u64 expv = tag_pat((t - 1) % 15);
      const f16* hp = hbuf + (size_t)((t - 1) & 7) * HBUF_SZ + (grow0 + l15) * KP + lk * 8;
      u64 q0[NKT], q1[NKT];
#pragma unroll
      for (int kt = 0; kt < NKT; ++kt) {      // first pass: all 20 in flight
        const u64* p = reinterpret_cast<const u64*>(hp + kt * 32);
        q0[kt] = __hip_atomic_load(p,     __ATOMIC_RELAXED, __HIP_MEMORY_SCOPE_AGENT);
        q1[kt] = __hip_atomic_load(p + 1, __ATOMIC_RELAXED, __HIP_MEMORY_SCOPE_AGENT);
      }
      bool any = true;
      int guard = 0;
      while (any && guard++ < (1 << 15)) {    // each pass = 1 RTT for all stale
        any = false;
#pragma unroll
        for (int kt = 0; kt < NKT; ++kt) {
          const u64* p = reinterpret_cast<const u64*>(hp + kt * 32);
          if ((q0[kt] & TAGMASK) != expv) {
            q0[kt] = __hip_atomic_load(p,     __ATOMIC_RELAXED, __HIP_MEMORY_SCOPE_AGENT);
            any = true;
          }
          if ((q1[kt] & TAGMASK) != expv) {
            q1[kt] = __hip_atomic_load(p + 1, __ATOMIC_RELAXED, __HIP_MEMORY_SCOPE_AGENT);
            any = true;
          }
        }
      }
#pragma unroll
      for (int kt = 0; kt < NKT; ++kt) {
        union { u64 qq[2]; f16x8 v; } u;
        u.qq[0] = q0[kt]; u.qq[1] = q1[kt];
#pragma unroll
        for (int j = 0; j < NTPG; ++j)
          acc[j] = __builtin_amdgcn_mfma_f32_16x16x32_f16(u.v, wh[j][kt], acc[j], 0, 0, 0);
      }
    }

    // ---- C-tiles -> LDS (parity buffer), one barrier per step ----
#pragma unroll
    for (int j = 0; j < NTPG; ++j)
      *reinterpret_cast<f32x4*>(&gates[par + gaddr[j]]) = acc[j];
    __syncthreads();

    // ---- elementwise + tagged h published via atomic EXCHANGE (RMW at L3:
    //      visibility is immediate, not eviction-driven) ----
    {
      const u64 pat = tag_pat(t % 15);
      f16* hc = hbuf + (size_t)(t & 7) * HBUF_SZ;
      for (int i = tid; i < 320; i += TPB) {   // (row, col-quad)
        int row = i & 15, qd = i >> 4;
        union { unsigned short us[4]; u64 uu; } pu;
#pragma unroll
        for (int e = 0; e < 4; ++e) {
          int cc = qd * 4 + e;
          float h = 0.f;
          if (cc < SL) {
            int base = cc * 20 + row;
            if (t < len_lds[row]) {
              float vi = gates[par + (0 * 80 + cc) * 20 + row];
              float vf = gates[par + (1 * 80 + cc) * 20 + row];
              float vg = gates[par + (2 * 80 + cc) * 20 + row];
              float vo = gates[par + (3 * 80 + cc) * 20 + row];
              float iv = sigf(vi), fv = sigf(vf), ov = sigf(vo);
              float gv = tanhf_(vg);
              float cn = fv * c_lds[base] + iv * gv;
              h = ov * tanhf_(cn);
              c_lds[base] = cn;
              hf_lds[base] = h;
            } else {
              h = hf_lds[base];
            }
          }
          union { f16 f; unsigned short u; } cv;
          cv.f = (f16)h;
          pu.us[e] = cv.u;
        }
        pu.uu = (pu.uu & ~TAGMASK) | pat;      // tag in bit0 of each fp16
        u64* dst = reinterpret_cast<u64*>(hc + (size_t)(grow0 + row) * KP + n * SLP + qd * 4);
        (void)__hip_atomic_exchange(dst, pu.uu, __ATOMIC_RELAXED, __HIP_MEMORY_SCOPE_AGENT);
      }
    }

    // ---- x-part of t+1 overlaps partner skew + our RMWs in flight ----
    if (t + 1 < maxlen) xpart(t + 1);
  }

  __syncthreads();
  for (int i = tid; i < 16 * SL; i += TPB) {
    int row = i & 15, cc = i >> 4;
    hf32[(grow0 + row) * ND + n * SL + cc] = hf_lds[cc * 20 + row];
  }
}

__global__ __launch_bounds__(256) void absa_logits(
    const float* __restrict__ hf32, const float* __restrict__ Wout,
    const float* __restrict__ bout, float* __restrict__ out) {
  int row = blockIdx.x * 4 + (threadIdx.x >> 6);   // 1 wave per batch row
  int l   = threadIdx.x & 63;
  float s0 = 0.f, s1 = 0.f, s2 = 0.f;
  for (int k = l; k < ND; k += 64) {
    float h  = hf32[row * ND + k];
    s0 += h * Wout[k * 3 + 0];
    s1 += h * Wout[k * 3 + 1];
    s2 += h * Wout[k * 3 + 2];
  }
#pragma unroll
  for (int o = 32; o; o >>= 1) {
    s0 += __shfl_down(s0, o);
    s1 += __shfl_down(s1, o);
    s2 += __shfl_down(s2, o);
  }
  if (l == 0) {
    out[row * 3 + 0] = s0 + bout[0];
    out[row * 3 + 1] = s1 + bout[1];
    out[row * 3 + 2] = s2 + bout[2];
  }
}

extern "C" void kernel_launch(void* const* d_in, const int* in_sizes, int n_in,
                              void* d_out, int out_size, void* d_ws, size_t ws_size,
                              hipStream_t stream) {
  const int*   sent = (const int*)d_in[0];
  const int*   lens = (const int*)d_in[1];
  const float* emb  = (const float*)d_in[2];
  const float* Wx   = (const float*)d_in[3];
  const float* Wh   = (const float*)d_in[4];
  const float* bv   = (const float*)d_in[5];
  const float* Wout = (const float*)d_in[6];
  const float* bout = (const float*)d_in[7];
  float* out = (float*)d_out;

  char* wsb = (char*)d_ws;
  f16*   embb = (f16*)(wsb + OFF_EMB);
  f16*   whp  = (f16*)(wsb + OFF_WHP);
  f16*   wxp  = (f16*)(wsb + OFF_WXP);
  f16*   hbuf = (f16*)(wsb + OFF_HBUF);
  float* hf32 = (float*)(wsb + OFF_HF32);

  // virgin slabs = 0xFF: tag bits 1111 (=15, outside 0..14) + NaN fp16 data
  (void)hipMemsetAsync(hbuf, 0xFF, NSLAB * NB * KP * 2, stream);

  absa_prep_emb  <<<(NV * KP / 8 + 255) / 256, 256, 0, stream>>>(emb, embb);
  absa_prep_pack2<<<2 * 4 * NTIL * NKT * 512 / 256, 256, 0, stream>>>(Wx, Wh, bv, wxp, whp);
  absa_lstm      <<<GRID, TPB, 0, stream>>>(sent, lens, embb, whp, wxp, hbuf, hf32);
  absa_logits    <<<NB / 4, 256, 0, stream>>>(hf32, Wout, bout, out);
}